// Round 3
// baseline (85.279 us; speedup 1.0000x reference)
//
#include <hip/hip_runtime.h>
#include <math.h>

typedef __attribute__((ext_vector_type(8))) short s8v;   // 8 bf16 (4 VGPRs)
typedef __attribute__((ext_vector_type(4))) float f4v;   // MFMA accumulator

constexpr int E_TOTAL = 320000;
constexpr int NODE_D  = 256;   // D
constexpr int K2      = 512;   // 2D
constexpr int H       = 64;

// workspace layout (bytes)
constexpr unsigned XBF_ROWB = NODE_D * 2;            // 512 B per node row (bf16)
constexpr size_t   WT_OFF   = 10000ull * XBF_ROWB;   // 5,120,000 (16B aligned)

__device__ __forceinline__ unsigned short f2bf(float f) {
    unsigned u = __float_as_uint(f);
    u += 0x7fffu + ((u >> 16) & 1u);   // RNE
    return (unsigned short)(u >> 16);
}

__device__ __forceinline__ float concrete_gate(float la, float u) {
    float z = (la + logf(u) - log1pf(-u)) * 10.0f;
    return 1.0f / (1.0f + expf(-z));
}

#define GLDS16(gsrc, ldst) \
    __builtin_amdgcn_global_load_lds((const __attribute__((address_space(1))) unsigned int*)(gsrc), \
                                     (__attribute__((address_space(3))) unsigned int*)(ldst), 16, 0, 0)

// ---------------- fused prep: x->bf16 | W1 -> swizzled W1^T bf16 | weight gates
// grid: [0,1250) conv_x | [1250,1266) conv_w | [1266,1650) wgate
__global__ void prep_kernel(const float* __restrict__ x,
                            const float* __restrict__ W1,
                            const float* __restrict__ wla1,
                            const float* __restrict__ wla2,
                            const float* __restrict__ u1,
                            const float* __restrict__ u2,
                            float* __restrict__ out,
                            char* __restrict__ ws)
{
    const int bid = blockIdx.x;
    const int t   = threadIdx.x;

    if (bid < 1250) {                                   // ---- x -> bf16 (8 floats/thread)
        int tid = bid * 256 + t;                        // 0..319999
        const float4* p = (const float4*)x + (size_t)tid * 2;
        float4 a = p[0], b = p[1];
        unsigned short r[8] = { f2bf(a.x), f2bf(a.y), f2bf(a.z), f2bf(a.w),
                                f2bf(b.x), f2bf(b.y), f2bf(b.z), f2bf(b.w) };
        *(uint4*)(ws + (size_t)tid * 16) = *(const uint4*)r;
    } else if (bid < 1266) {                            // ---- W1[512][64] -> swizzled W1^T image
        int tid = (bid - 1250) * 256 + t;               // 0..4095
        int c  = tid >> 6;                              // col 0..63
        int kb = tid & 63;                              // 16B chunk (8 k) 0..63
        int k0 = kb * 8;
        unsigned short r[8];
        #pragma unroll
        for (int q = 0; q < 8; ++q)
            r[q] = f2bf(W1[(size_t)(k0 + q) * H + c]);
        unsigned dst = (unsigned)c * 1024u + (((unsigned)kb * 16u) ^ (((unsigned)(c & 7)) << 4));
        *(uint4*)(ws + WT_OFF + dst) = *(const uint4*)r;
    } else {                                            // ---- weight gates
        int tid = (bid - 1266) * 256 + t;               // 0..98303
        const float4* la4; const float4* u4; float4* o4; int idx;
        if (tid < 65536) { la4 = (const float4*)wla1; u4 = (const float4*)u1; o4 = (float4*)(out + 320000); idx = tid; }
        else             { la4 = (const float4*)wla2; u4 = (const float4*)u2; o4 = (float4*)(out + 582144); idx = tid - 65536; }
        float4 la = la4[idx], u = u4[idx], rr;
        rr.x = concrete_gate(la.x, u.x);
        rr.y = concrete_gate(la.y, u.y);
        rr.z = concrete_gate(la.z, u.z);
        rr.w = concrete_gate(la.w, u.w);
        o4[idx] = rr;
    }
}

// ---------------- edge MLP: barrier-free K-loop, A gathered global->reg, B whole-K in LDS
__global__ __launch_bounds__(512, 4)
void edge_mlp_mfma(const unsigned short* __restrict__ xbf,   // [10000][256] bf16
                   const char*           __restrict__ wtsw,  // swizzled W1^T image, 64 KB
                   const int*   __restrict__ eidx,
                   const float* __restrict__ la,
                   const float* __restrict__ b1,
                   const float* __restrict__ W2,
                   const float* __restrict__ b2,
                   const float* __restrict__ ue,
                   float* __restrict__ out)
{
    __shared__ unsigned short sB[H][K2];   // 64 KB, swizzled image of W1^T

    const int t    = threadIdx.x;
    const int lane = t & 63;
    const int w    = t >> 6;               // wave 0..7, owns 64 edges
    const int e0   = blockIdx.x * 512;

    // ---- stage whole B (64 KB) once: 8 x 1KB chunks per wave, linear copy
    {
        char* sBb = (char*)&sB[0][0];
        #pragma unroll
        for (int i = 0; i < 8; ++i) {
            int cid = i * 8 + w;
            GLDS16(wtsw + cid * 1024 + lane * 16, sBb + cid * 1024);
        }
    }

    const int cg = lane & 15;              // A/B row-col within frag; C col
    const int rg = lane >> 4;              // k-group; C row group

    // per-lane A row byte offsets (rg*16 folded in)
    unsigned offI[4], offJ[4];
    #pragma unroll
    for (int ar = 0; ar < 4; ++ar) {
        int e = e0 + w * 64 + ar * 16 + cg;
        offI[ar] = (unsigned)eidx[e]           * XBF_ROWB + (unsigned)rg * 16u;
        offJ[ar] = (unsigned)eidx[E_TOTAL + e] * XBF_ROWB + (unsigned)rg * 16u;
    }
    const char* xb = (const char*)xbf;

    // B ds base: col cg, swizzled; ks folds in via XOR (disjoint bits), bc via +16384
    const unsigned dsC = (unsigned)cg * 1024u + (((unsigned)rg * 16u) ^ (((unsigned)(cg & 7)) << 4));
    const char* sBb = (const char*)&sB[0][0];

    f4v acc[4][4] = {};

    __syncthreads();                       // B resident (drains the global_load_lds queue)

    #pragma unroll
    for (int ks = 0; ks < 16; ++ks) {
        const unsigned kA = (unsigned)(ks & 7) * 64u;
        s8v af[4], bfv[4];
        #pragma unroll
        for (int ar = 0; ar < 4; ++ar) {
            const unsigned off = (ks < 8 ? offI[ar] : offJ[ar]) + kA;
            af[ar] = *(const s8v*)(xb + off);
        }
        const unsigned bAddr = dsC ^ ((unsigned)ks * 64u);
        #pragma unroll
        for (int bc = 0; bc < 4; ++bc)
            bfv[bc] = *(const s8v*)(sBb + bAddr + (unsigned)bc * 16384u);
        #pragma unroll
        for (int ar = 0; ar < 4; ++ar)
            #pragma unroll
            for (int bc = 0; bc < 4; ++bc)
                acc[ar][bc] = __builtin_amdgcn_mfma_f32_16x16x32_bf16(af[ar], bfv[bc], acc[ar][bc], 0, 0, 0);
    }

    // ---- epilogue: h = relu(acc + b1), sim = h @ W2 + b2, out = sim * gate
    float b1v[4], w2v[4];
    #pragma unroll
    for (int bc = 0; bc < 4; ++bc) {
        b1v[bc] = b1[bc * 16 + cg];
        w2v[bc] = W2[bc * 16 + cg];
    }
    const float bias2 = b2[0];

    #pragma unroll
    for (int ar = 0; ar < 4; ++ar) {
        #pragma unroll
        for (int reg = 0; reg < 4; ++reg) {
            float s = 0.0f;
            #pragma unroll
            for (int bc = 0; bc < 4; ++bc) {
                float h = acc[ar][bc][reg] + b1v[bc];
                h = fmaxf(h, 0.0f);
                s = fmaf(h, w2v[bc], s);
            }
            s += __shfl_xor(s, 1);
            s += __shfl_xor(s, 2);
            s += __shfl_xor(s, 4);
            s += __shfl_xor(s, 8);
            if (cg == 0) {
                int e = e0 + w * 64 + ar * 16 + rg * 4 + reg;
                out[e] = (s + bias2) * concrete_gate(la[e], ue[e]);
            }
        }
    }
}

extern "C" void kernel_launch(void* const* d_in, const int* in_sizes, int n_in,
                              void* d_out, int out_size, void* d_ws, size_t ws_size,
                              hipStream_t stream) {
    const float* x    = (const float*)d_in[0];
    const int*   ei   = (const int*)  d_in[1];
    const float* la   = (const float*)d_in[2];
    const float* W1   = (const float*)d_in[3];
    const float* b1   = (const float*)d_in[4];
    const float* W2   = (const float*)d_in[5];
    const float* b2   = (const float*)d_in[6];
    const float* wla1 = (const float*)d_in[7];
    const float* wla2 = (const float*)d_in[8];
    const float* ue   = (const float*)d_in[9];
    const float* u1   = (const float*)d_in[10];
    const float* u2   = (const float*)d_in[11];
    float* out = (float*)d_out;
    char*  ws  = (char*)d_ws;

    hipLaunchKernelGGL(prep_kernel, dim3(1650), dim3(256), 0, stream,
                       x, W1, wla1, wla2, u1, u2, out, ws);
    hipLaunchKernelGGL(edge_mlp_mfma, dim3(E_TOTAL / 512), dim3(512), 0, stream,
                       (const unsigned short*)ws, ws + WT_OFF,
                       ei, la, b1, W2, b2, ue, out);
}

// Round 4
// 43.682 us; speedup vs baseline: 1.9523x; 1.9523x over previous
//
#include <hip/hip_runtime.h>
#include <math.h>

typedef __attribute__((ext_vector_type(8))) short s8v;   // 8 bf16 (4 VGPRs)
typedef __attribute__((ext_vector_type(4))) float f4v;   // MFMA accumulator

constexpr int E_TOTAL = 320000;
constexpr int NODE_N  = 10000;
constexpr int NODE_D  = 256;   // D (K of node GEMM)
constexpr int H       = 64;
constexpr int NC      = 128;   // node-GEMM N = 2H (P | Q)

// workspace layout (bytes)
constexpr size_t PQ_OFF = 0;                               // [10000][128] bf16 = 2,560,000 B
constexpr size_t WT_OFF = 2560000;                         // swizzled W'^T image, 64 KB

__device__ __forceinline__ unsigned short f2bf(float f) {
    unsigned u = __float_as_uint(f);
    u += 0x7fffu + ((u >> 16) & 1u);   // RNE
    return (unsigned short)(u >> 16);
}

__device__ __forceinline__ float concrete_gate(float la, float u) {
    float z = (la + logf(u) - log1pf(-u)) * 10.0f;
    return 1.0f / (1.0f + expf(-z));
}

#define GLDS16(gsrc, ldst) \
    __builtin_amdgcn_global_load_lds((const __attribute__((address_space(1))) unsigned int*)(gsrc), \
                                     (__attribute__((address_space(3))) unsigned int*)(ldst), 16, 0, 0)

// ---------------- prep: W1[512][64] -> swizzled W'^T bf16 image [128][256] | weight gates
// W'[k][c] (k<256): c<64 ? W1[k][c] : W1[256+k][c-64].  Image row c = 512 B,
// 16B granule g at byte c*512 + ((g*16) ^ ((c&7)<<4)).
__global__ void prep_kernel(const float* __restrict__ W1,
                            const float* __restrict__ wla1,
                            const float* __restrict__ wla2,
                            const float* __restrict__ u1,
                            const float* __restrict__ u2,
                            float* __restrict__ out,
                            char* __restrict__ ws)
{
    const int bid = blockIdx.x;
    const int t   = threadIdx.x;

    if (bid < 16) {                                     // ---- W' swizzled image (4096 threads)
        int tid = bid * 256 + t;                        // 0..4095
        int c = tid >> 5;                               // col 0..127
        int g = tid & 31;                               // 16B granule 0..31 (8 k each)
        int k0 = g * 8;
        unsigned short r[8];
        #pragma unroll
        for (int qq = 0; qq < 8; ++qq) {
            int k = k0 + qq;
            float v = (c < 64) ? W1[(size_t)k * H + c] : W1[(size_t)(256 + k) * H + (c - 64)];
            r[qq] = f2bf(v);
        }
        unsigned dst = (unsigned)c * 512u + (((unsigned)g * 16u) ^ (((unsigned)(c & 7)) << 4));
        *(uint4*)(ws + WT_OFF + dst) = *(const uint4*)r;
    } else {                                            // ---- weight gates (98304 f4-threads)
        int tid = (bid - 16) * 256 + t;
        const float4* la4; const float4* u4; float4* o4; int idx;
        if (tid < 65536) { la4 = (const float4*)wla1; u4 = (const float4*)u1; o4 = (float4*)(out + 320000); idx = tid; }
        else             { la4 = (const float4*)wla2; u4 = (const float4*)u2; o4 = (float4*)(out + 582144); idx = tid - 65536; }
        float4 la = la4[idx], u = u4[idx], rr;
        rr.x = concrete_gate(la.x, u.x);
        rr.y = concrete_gate(la.y, u.y);
        rr.z = concrete_gate(la.z, u.z);
        rr.w = concrete_gate(la.w, u.w);
        o4[idx] = rr;
    }
}

// ---------------- node GEMM: C[10000][128] = x @ [W1a | W1b], bf16 out
// 256 threads = 4 waves x 64 rows; whole W'^T (64 KB) in LDS; K-loop barrier-free.
__global__ __launch_bounds__(256, 2)
void node_gemm(const float* __restrict__ x,
               const char*  __restrict__ wtsw,
               unsigned short* __restrict__ pq)
{
    __shared__ char sB[65536];

    const int t    = threadIdx.x;
    const int lane = t & 63;
    const int w    = t >> 6;
    const int cg   = lane & 15;
    const int rg   = lane >> 4;
    const int rowBase = blockIdx.x * 256 + w * 64;

    // stage swizzled image linearly: wave w covers [w*16K, w*16K+16K)
    #pragma unroll
    for (int c = 0; c < 16; ++c) {
        unsigned off = (unsigned)w * 16384u + (unsigned)c * 1024u;
        GLDS16(wtsw + off + lane * 16, sB + off);
    }

    // A row pointers (clamped), k-offset rg*8 floats folded in
    const float* xr[4];
    #pragma unroll
    for (int ar = 0; ar < 4; ++ar) {
        int r = rowBase + ar * 16 + cg;
        if (r > NODE_N - 1) r = NODE_N - 1;
        xr[ar] = x + (size_t)r * NODE_D + rg * 8;
    }

    f4v acc[4][8] = {};
    const unsigned swz = ((unsigned)(cg & 7)) << 4;

    __syncthreads();   // W'^T resident

    #pragma unroll
    for (int ks = 0; ks < 8; ++ks) {
        s8v af[4];
        #pragma unroll
        for (int ar = 0; ar < 4; ++ar) {
            float4 u0 = *(const float4*)(xr[ar] + ks * 32);
            float4 u1 = *(const float4*)(xr[ar] + ks * 32 + 4);
            unsigned short rr[8] = { f2bf(u0.x), f2bf(u0.y), f2bf(u0.z), f2bf(u0.w),
                                     f2bf(u1.x), f2bf(u1.y), f2bf(u1.z), f2bf(u1.w) };
            af[ar] = *(const s8v*)rr;
        }
        const unsigned kb = ((unsigned)ks * 64u + (unsigned)rg * 16u) ^ swz;
        s8v bfv[8];
        #pragma unroll
        for (int bc = 0; bc < 8; ++bc)
            bfv[bc] = *(const s8v*)(sB + (unsigned)(bc * 16 + cg) * 512u + kb);
        #pragma unroll
        for (int ar = 0; ar < 4; ++ar)
            #pragma unroll
            for (int bc = 0; bc < 8; ++bc)
                acc[ar][bc] = __builtin_amdgcn_mfma_f32_16x16x32_bf16(af[ar], bfv[bc], acc[ar][bc], 0, 0, 0);
    }

    // store bf16: C row = rowBase + ar*16 + rg*4 + reg, col = bc*16 + cg
    #pragma unroll
    for (int ar = 0; ar < 4; ++ar) {
        #pragma unroll
        for (int reg = 0; reg < 4; ++reg) {
            int row = rowBase + ar * 16 + rg * 4 + reg;
            if (row < NODE_N) {
                #pragma unroll
                for (int bc = 0; bc < 8; ++bc)
                    pq[(size_t)row * NC + bc * 16 + cg] = f2bf(acc[ar][bc][reg]);
            }
        }
    }
}

// ---------------- edge pass: out[e] = (sum_c relu(P[i][c]+Q[j][c]+b1[c]) * W2[c] + b2) * gate
// 4 lanes per edge (16 cols each); 64 edges per 256-thread block.
__global__ __launch_bounds__(256, 4)
void edge_pass(const unsigned short* __restrict__ pq,
               const int*   __restrict__ eidx,
               const float* __restrict__ la,
               const float* __restrict__ b1,
               const float* __restrict__ W2,
               const float* __restrict__ b2,
               const float* __restrict__ ue,
               float* __restrict__ out)
{
    const int t = threadIdx.x;
    const int q = t & 3;
    const int e = blockIdx.x * 64 + (t >> 2);

    const int i = eidx[e];
    const int j = eidx[E_TOTAL + e];

    const uint4* Pp = (const uint4*)(pq + (size_t)i * NC + q * 16);
    const uint4* Qp = (const uint4*)(pq + (size_t)j * NC + 64 + q * 16);
    uint4 p0 = Pp[0], p1 = Pp[1];
    uint4 q0 = Qp[0], q1 = Qp[1];

    float bb[16], ww[16];
    #pragma unroll
    for (int m = 0; m < 4; ++m) {
        *(float4*)&bb[4 * m] = *(const float4*)(b1 + q * 16 + 4 * m);
        *(float4*)&ww[4 * m] = *(const float4*)(W2 + q * 16 + 4 * m);
    }

    unsigned P8[8] = { p0.x, p0.y, p0.z, p0.w, p1.x, p1.y, p1.z, p1.w };
    unsigned Q8[8] = { q0.x, q0.y, q0.z, q0.w, q1.x, q1.y, q1.z, q1.w };

    float s = 0.0f;
    #pragma unroll
    for (int m = 0; m < 8; ++m) {
        float pl = __uint_as_float(P8[m] << 16);
        float ph = __uint_as_float(P8[m] & 0xffff0000u);
        float ql = __uint_as_float(Q8[m] << 16);
        float qh = __uint_as_float(Q8[m] & 0xffff0000u);
        float h0 = fmaxf(pl + ql + bb[2 * m], 0.0f);
        float h1 = fmaxf(ph + qh + bb[2 * m + 1], 0.0f);
        s = fmaf(h0, ww[2 * m], s);
        s = fmaf(h1, ww[2 * m + 1], s);
    }
    s += __shfl_xor(s, 1);
    s += __shfl_xor(s, 2);

    if (q == 0) {
        float sim = s + b2[0];
        out[e] = sim * concrete_gate(la[e], ue[e]);
    }
}

extern "C" void kernel_launch(void* const* d_in, const int* in_sizes, int n_in,
                              void* d_out, int out_size, void* d_ws, size_t ws_size,
                              hipStream_t stream) {
    const float* x    = (const float*)d_in[0];
    const int*   ei   = (const int*)  d_in[1];
    const float* la   = (const float*)d_in[2];
    const float* W1   = (const float*)d_in[3];
    const float* b1   = (const float*)d_in[4];
    const float* W2   = (const float*)d_in[5];
    const float* b2   = (const float*)d_in[6];
    const float* wla1 = (const float*)d_in[7];
    const float* wla2 = (const float*)d_in[8];
    const float* ue   = (const float*)d_in[9];
    const float* u1   = (const float*)d_in[10];
    const float* u2   = (const float*)d_in[11];
    float* out = (float*)d_out;
    char*  ws  = (char*)d_ws;

    hipLaunchKernelGGL(prep_kernel, dim3(400), dim3(256), 0, stream,
                       W1, wla1, wla2, u1, u2, out, ws);
    hipLaunchKernelGGL(node_gemm, dim3(40), dim3(256), 0, stream,
                       x, ws + WT_OFF, (unsigned short*)(ws + PQ_OFF));
    hipLaunchKernelGGL(edge_pass, dim3(E_TOTAL / 64), dim3(256), 0, stream,
                       (const unsigned short*)(ws + PQ_OFF), ei, la, b1, W2, b2, ue, out);
}

// Round 5
// 39.512 us; speedup vs baseline: 2.1583x; 1.1055x over previous
//
#include <hip/hip_runtime.h>
#include <math.h>

typedef __attribute__((ext_vector_type(8))) short s8v;   // 8 bf16 (4 VGPRs)
typedef __attribute__((ext_vector_type(4))) float f4v;   // MFMA accumulator

constexpr int E_TOTAL = 320000;
constexpr int NODE_N  = 10000;
constexpr int NODE_D  = 256;   // D (K of node GEMM)
constexpr int H       = 64;
constexpr int NC      = 128;   // node-GEMM N = 2H (P | Q)

// workspace layout (bytes)
constexpr size_t PQ_OFF = 0;          // [10000][128] bf16 = 2,560,000 B
constexpr size_t WT_OFF = 2560000;    // W'^T bf16 [128][256] = 64 KB (unswizzled)

__device__ __forceinline__ unsigned short f2bf(float f) {
    unsigned u = __float_as_uint(f);
    u += 0x7fffu + ((u >> 16) & 1u);   // RNE
    return (unsigned short)(u >> 16);
}

// sigmoid((la + log u - log1p(-u))/0.1) = 1 / (1 + e^{-10 la} * ((1-u)/u)^10)
// r^10 -> inf / 0 saturation yields exactly the correct gate limits (0 / 1).
__device__ __forceinline__ float fast_gate(float la, float u) {
    float r  = (1.0f - u) * __builtin_amdgcn_rcpf(u);
    float r2 = r * r, r4 = r2 * r2, r8 = r4 * r4;
    float t  = __expf(-10.0f * la) * (r8 * r2);
    return 1.0f / (1.0f + t);
}

// ---------------- K1: W1 -> W'^T bf16 image (16 blocks) | weight gates (384 blocks)
// W'[k][c] (k<256): c<64 ? W1[k][c] : W1[256+k][c-64]; image row c = 256 bf16.
__global__ void prep_kernel(const float* __restrict__ W1,
                            const float* __restrict__ wla1,
                            const float* __restrict__ wla2,
                            const float* __restrict__ u1,
                            const float* __restrict__ u2,
                            float* __restrict__ out,
                            unsigned short* __restrict__ wt)
{
    const int bid = blockIdx.x;
    const int t   = threadIdx.x;

    if (bid < 16) {                                     // ---- W'^T image (4096 threads)
        int tid = bid * 256 + t;                        // 0..4095
        int c  = tid >> 5;                              // col 0..127
        int g  = tid & 31;                              // 16B granule (8 k's)
        int k0 = g * 8;
        unsigned short r[8];
        #pragma unroll
        for (int q = 0; q < 8; ++q) {
            int k = k0 + q;
            float v = (c < 64) ? W1[(size_t)k * H + c] : W1[(size_t)(256 + k) * H + (c - 64)];
            r[q] = f2bf(v);
        }
        *(uint4*)(wt + (size_t)c * 256 + k0) = *(const uint4*)r;
    } else {                                            // ---- weight gates
        int tid = (bid - 16) * 256 + t;                 // 0..98303
        const float4* la4; const float4* u4; float4* o4; int idx;
        if (tid < 65536) { la4 = (const float4*)wla1; u4 = (const float4*)u1; o4 = (float4*)(out + 320000); idx = tid; }
        else             { la4 = (const float4*)wla2; u4 = (const float4*)u2; o4 = (float4*)(out + 582144); idx = tid - 65536; }
        float4 la = la4[idx], u = u4[idx], rr;
        rr.x = fast_gate(la.x, u.x);
        rr.y = fast_gate(la.y, u.y);
        rr.z = fast_gate(la.z, u.z);
        rr.w = fast_gate(la.w, u.w);
        o4[idx] = rr;
    }
}

// ---------------- K2: node GEMM C[10000][128] = x @ [W1a|W1b], bf16 out.
// 313 blocks x 256 thr; waves split 2M x 2N; B-frags read global->reg (L1/L2-hot);
// no LDS, no barriers.
__global__ void node_gemm(const float* __restrict__ x,
                          const unsigned short* __restrict__ wt,
                          unsigned short* __restrict__ pq)
{
    const int t    = threadIdx.x;
    const int lane = t & 63;
    const int w    = t >> 6;
    const int cg   = lane & 15;
    const int rg   = lane >> 4;
    const int mw   = w >> 1;           // M half
    const int nw   = w & 1;            // N half (64 cols)
    const int rowBase = blockIdx.x * 32 + mw * 16;

    int arow = rowBase + cg;
    if (arow > NODE_N - 1) arow = NODE_N - 1;
    const float* xr = x + (size_t)arow * NODE_D + rg * 8;

    const unsigned short* wbase = wt + (size_t)(nw * 64 + cg) * 256 + rg * 8;

    f4v acc[4] = {};
    #pragma unroll
    for (int ks = 0; ks < 8; ++ks) {
        float4 u0 = *(const float4*)(xr + ks * 32);
        float4 u1 = *(const float4*)(xr + ks * 32 + 4);
        unsigned short rr[8] = { f2bf(u0.x), f2bf(u0.y), f2bf(u0.z), f2bf(u0.w),
                                 f2bf(u1.x), f2bf(u1.y), f2bf(u1.z), f2bf(u1.w) };
        s8v af = *(const s8v*)rr;
        #pragma unroll
        for (int bc = 0; bc < 4; ++bc) {
            s8v bf = *(const s8v*)(wbase + (size_t)bc * 16 * 256 + ks * 32);
            acc[bc] = __builtin_amdgcn_mfma_f32_16x16x32_bf16(af, bf, acc[bc], 0, 0, 0);
        }
    }

    // C row = rowBase + rg*4 + reg, col = nw*64 + bc*16 + cg
    #pragma unroll
    for (int reg = 0; reg < 4; ++reg) {
        int row = rowBase + rg * 4 + reg;
        if (row < NODE_N) {
            #pragma unroll
            for (int bc = 0; bc < 4; ++bc)
                pq[(size_t)row * NC + nw * 64 + bc * 16 + cg] = f2bf(acc[bc][reg]);
        }
    }
}

// ---------------- K3: edge pass. out[e] = (sum_c relu(P[i][c]+Q[j][c]+b1[c])*W2[c] + b2) * gate
// 4 lanes per edge (16 cols each); 64 edges per 256-thread block; PQ is L2-resident.
__global__ __launch_bounds__(256, 4)
void edge_pass(const unsigned short* __restrict__ pq,
               const int*   __restrict__ eidx,
               const float* __restrict__ la,
               const float* __restrict__ b1,
               const float* __restrict__ W2,
               const float* __restrict__ b2,
               const float* __restrict__ ue,
               float* __restrict__ out)
{
    const int t = threadIdx.x;
    const int q = t & 3;
    const int e = blockIdx.x * 64 + (t >> 2);

    const int i = eidx[e];
    const int j = eidx[E_TOTAL + e];

    const uint4* Pp = (const uint4*)(pq + (size_t)i * NC + q * 16);
    const uint4* Qp = (const uint4*)(pq + (size_t)j * NC + 64 + q * 16);
    uint4 p0 = Pp[0], p1 = Pp[1];
    uint4 q0 = Qp[0], q1 = Qp[1];

    float bb[16], ww[16];
    #pragma unroll
    for (int m = 0; m < 4; ++m) {
        *(float4*)&bb[4 * m] = *(const float4*)(b1 + q * 16 + 4 * m);
        *(float4*)&ww[4 * m] = *(const float4*)(W2 + q * 16 + 4 * m);
    }

    unsigned P8[8] = { p0.x, p0.y, p0.z, p0.w, p1.x, p1.y, p1.z, p1.w };
    unsigned Q8[8] = { q0.x, q0.y, q0.z, q0.w, q1.x, q1.y, q1.z, q1.w };

    float s = 0.0f;
    #pragma unroll
    for (int m = 0; m < 8; ++m) {
        float pl = __uint_as_float(P8[m] << 16);
        float ph = __uint_as_float(P8[m] & 0xffff0000u);
        float ql = __uint_as_float(Q8[m] << 16);
        float qh = __uint_as_float(Q8[m] & 0xffff0000u);
        float h0 = fmaxf(pl + ql + bb[2 * m], 0.0f);
        float h1 = fmaxf(ph + qh + bb[2 * m + 1], 0.0f);
        s = fmaf(h0, ww[2 * m], s);
        s = fmaf(h1, ww[2 * m + 1], s);
    }
    s += __shfl_xor(s, 1);
    s += __shfl_xor(s, 2);

    if (q == 0) {
        float sim = s + b2[0];
        out[e] = sim * fast_gate(la[e], ue[e]);
    }
}

extern "C" void kernel_launch(void* const* d_in, const int* in_sizes, int n_in,
                              void* d_out, int out_size, void* d_ws, size_t ws_size,
                              hipStream_t stream) {
    const float* x    = (const float*)d_in[0];
    const int*   ei   = (const int*)  d_in[1];
    const float* la   = (const float*)d_in[2];
    const float* W1   = (const float*)d_in[3];
    const float* b1   = (const float*)d_in[4];
    const float* W2   = (const float*)d_in[5];
    const float* b2   = (const float*)d_in[6];
    const float* wla1 = (const float*)d_in[7];
    const float* wla2 = (const float*)d_in[8];
    const float* ue   = (const float*)d_in[9];
    const float* u1   = (const float*)d_in[10];
    const float* u2   = (const float*)d_in[11];
    float* out = (float*)d_out;
    char*  ws  = (char*)d_ws;

    unsigned short* pq = (unsigned short*)(ws + PQ_OFF);
    unsigned short* wt = (unsigned short*)(ws + WT_OFF);

    hipLaunchKernelGGL(prep_kernel, dim3(400), dim3(256), 0, stream,
                       W1, wla1, wla2, u1, u2, out, wt);
    hipLaunchKernelGGL(node_gemm, dim3(313), dim3(256), 0, stream, x, wt, pq);
    hipLaunchKernelGGL(edge_pass, dim3(E_TOTAL / 64), dim3(256), 0, stream,
                       pq, ei, la, b1, W2, b2, ue, out);
}